// Round 6
// baseline (708.112 us; speedup 1.0000x reference)
//
#include <hip/hip_runtime.h>
#include <math.h>

// Problem constants
#define NTOK 4096
#define PCH  128
#define ICH  256
#define OCH  128
#define NB   2
#define SCALEF 0.08838834764831845f   // 1/sqrt(128)
#define SCALE2 0.12751743f            // SCALEF * log2(e)

typedef __bf16 bf16_t;
typedef __attribute__((ext_vector_type(8))) __bf16 bf16x8;
typedef __attribute__((ext_vector_type(4))) __bf16 bf16x4;
typedef __attribute__((ext_vector_type(4))) float floatx4;

#define LDK 136   // padded row length (bf16) for k=128 tiles

// ---------------------------------------------------------------------------
// K0: merged pack — y<2: pf -> pfC + pfT;  y>=2: img -> imgT (token-major)
// ---------------------------------------------------------------------------
__global__ __launch_bounds__(256) void pack_all(const float* __restrict__ pf,
                                                const float* __restrict__ img,
                                                bf16_t* __restrict__ pfC,
                                                bf16_t* __restrict__ pfT,
                                                bf16_t* __restrict__ imgT)
{
    __shared__ float Ls[64][65];
    const int t = threadIdx.x;
    const int n0 = blockIdx.x * 64, b = blockIdx.z;
    const bool ispf = blockIdx.y < 2;
    const int d0 = ispf ? blockIdx.y * 64 : (blockIdx.y - 2) * 64;
    const float* src = (ispf ? pf + ((size_t)(b * PCH + d0)) * NTOK
                             : img + ((size_t)(b * ICH + d0)) * NTOK) + n0;
#pragma unroll
    for (int p = 0; p < 4; p++) {
        int d = p * 16 + (t >> 4), c = t & 15;
        float4 v = *(const float4*)&src[d * NTOK + c * 4];
        Ls[d][c * 4 + 0] = v.x; Ls[d][c * 4 + 1] = v.y;
        Ls[d][c * 4 + 2] = v.z; Ls[d][c * 4 + 3] = v.w;
        if (ispf) {
            bf16x4 o = { (bf16_t)v.x, (bf16_t)v.y, (bf16_t)v.z, (bf16_t)v.w };
            *(bf16x4*)&pfC[((size_t)(b * PCH + d0 + d)) * NTOK + n0 + c * 4] = o;
        }
    }
    __syncthreads();
#pragma unroll
    for (int p = 0; p < 2; p++) {
        int n = p * 32 + (t >> 3), c = t & 7;
        bf16x8 o;
#pragma unroll
        for (int k = 0; k < 8; k++) o[k] = (bf16_t)Ls[c * 8 + k][n];
        if (ispf)
            *(bf16x8*)&pfT[((size_t)(b * NTOK + n0 + n)) * PCH + d0 + c * 8] = o;
        else
            *(bf16x8*)&imgT[((size_t)(b * NTOK + n0 + n)) * ICH + d0 + c * 8] = o;
    }
}

// ---------------------------------------------------------------------------
// K1: fc2 (MFMA) — ri[p][n] = sum_c w[p][c]*img[c][n] + bias[p]
// Also zeroes the zsum buffers (16384 floats) in its prologue.
// ---------------------------------------------------------------------------
__global__ __launch_bounds__(256) void fc2_mfma(const bf16_t* __restrict__ imgT,
                                                const float* __restrict__ w,
                                                const float* __restrict__ bias,
                                                bf16_t* __restrict__ riC,
                                                bf16_t* __restrict__ riT,
                                                float* __restrict__ zsums)
{
    const int t = threadIdx.x;
    if (blockIdx.y == 0 && blockIdx.z == 0)
        zsums[blockIdx.x * 256 + t] = 0.f;       // 64 blocks x 256 = 16384 floats

    const int n0 = blockIdx.x * 64, pbase = blockIdx.y * 64, b = blockIdx.z;
    const int lane = t & 63, wv = t >> 6, tx = lane & 15, q = lane >> 4;
    const int n = n0 + wv * 16 + tx;
    const bf16_t* trow = imgT + ((size_t)(b * NTOK + n)) * ICH;

    floatx4 acc[4];
#pragma unroll
    for (int ot = 0; ot < 4; ot++) acc[ot] = (floatx4){0.f, 0.f, 0.f, 0.f};

#pragma unroll
    for (int s = 0; s < 8; s++) {
        bf16x8 bf = *(const bf16x8*)&trow[s * 32 + q * 8];
#pragma unroll
        for (int ot = 0; ot < 4; ot++) {
            const float* wr = w + (size_t)(pbase + ot * 16 + tx) * ICH + s * 32 + q * 8;
            float4 x0 = *(const float4*)wr;
            float4 x1 = *(const float4*)(wr + 4);
            bf16x8 af;
            af[0] = (bf16_t)x0.x; af[1] = (bf16_t)x0.y; af[2] = (bf16_t)x0.z; af[3] = (bf16_t)x0.w;
            af[4] = (bf16_t)x1.x; af[5] = (bf16_t)x1.y; af[6] = (bf16_t)x1.z; af[7] = (bf16_t)x1.w;
            acc[ot] = __builtin_amdgcn_mfma_f32_16x16x32_bf16(af, bf, acc[ot], 0, 0, 0);
        }
    }

#pragma unroll
    for (int ot = 0; ot < 4; ot++) {
        bf16x4 tv;
#pragma unroll
        for (int r = 0; r < 4; r++) {
            const int p = pbase + ot * 16 + q * 4 + r;
            float v = acc[ot][r] + bias[p];
            tv[r] = (bf16_t)v;
            riC[((size_t)(b * PCH + p)) * NTOK + n] = (bf16_t)v;
        }
        *(bf16x4*)&riT[((size_t)(b * NTOK + n)) * PCH + pbase + ot * 16 + q * 4] = tv;
    }
}

// ---------------------------------------------------------------------------
// K2: stats v5 + XCD swizzle + fus-zero prologue (unchanged).
// ---------------------------------------------------------------------------
__global__ __launch_bounds__(256, 4) void stats_mfma(const bf16_t* __restrict__ pfT,
                                                     const bf16_t* __restrict__ riT,
                                                     float* __restrict__ zr,
                                                     float* __restrict__ zc,
                                                     float* __restrict__ fus)
{
    __shared__ bf16_t As[64 * LDK];
    __shared__ float zacc[1024];
    const int t = threadIdx.x;
    const int blk = blockIdx.x;

    { // zero fus: 512 blocks x 256 thr x 4 float4 = 2,097,152 floats exactly
        float4* f4 = (float4*)fus + ((size_t)blk * 256 + t) * 4;
        f4[0] = float4{0.f, 0.f, 0.f, 0.f};
        f4[1] = float4{0.f, 0.f, 0.f, 0.f};
        f4[2] = float4{0.f, 0.f, 0.f, 0.f};
        f4[3] = float4{0.f, 0.f, 0.f, 0.f};
    }

    const int g = blk & 7, slot = blk >> 3;      // XCD-aware decode
    const int b = g & 1, js = g >> 1;
    const bf16_t* At = pfT + (size_t)b * NTOK * PCH;
    const bf16_t* Bt = riT + (size_t)b * NTOK * PCH;
    float* zrow = zr + (size_t)b * NTOK;
    float* zcol = zc + (size_t)b * NTOK;
    const int lane = t & 63, w = t >> 6, tx = lane & 15, q = lane >> 4;
    const int i0 = slot * 64;
    const int jbase = js * 1024;
    const int sr = t >> 4, sc = t & 15;
    const bf16_t* Brow = Bt + (size_t)(jbase + w * 16 + tx) * PCH;

    bf16x8 bcur[4];
#pragma unroll
    for (int s = 0; s < 4; s++)
        bcur[s] = *(const bf16x8*)&Brow[s * 32 + q * 8];
#pragma unroll
    for (int p = 0; p < 4; p++) {
        int i = p * 16 + sr;
        *(uint4*)&As[i * LDK + sc * 8] = *(const uint4*)&At[((size_t)(i0 + i)) * PCH + sc * 8];
    }
    __syncthreads();
    bf16x8 af[4][4];
#pragma unroll
    for (int mt = 0; mt < 4; mt++)
#pragma unroll
        for (int s = 0; s < 4; s++)
            af[mt][s] = *(bf16x8*)&As[(mt * 16 + tx) * LDK + s * 32 + q * 8];

    float racc[4] = {0.f, 0.f, 0.f, 0.f};
    for (int jt = 0; jt < 16; jt++) {
        __builtin_amdgcn_s_barrier();            // pacing only
        floatx4 sacc[4];
#pragma unroll
        for (int mt = 0; mt < 4; mt++) {
            sacc[mt] = (floatx4){0.f, 0.f, 0.f, 0.f};
#pragma unroll
            for (int s = 0; s < 4; s++)
                sacc[mt] = __builtin_amdgcn_mfma_f32_16x16x32_bf16(bcur[s], af[mt][s], sacc[mt], 0, 0, 0);
        }
        if (jt < 15) {
            const bf16_t* bn = Brow + (size_t)(jt + 1) * 64 * PCH;
#pragma unroll
            for (int s = 0; s < 4; s++)
                bcur[s] = *(const bf16x8*)&bn[s * 32 + q * 8];
        }

        float ctmp[4] = {0.f, 0.f, 0.f, 0.f};
#pragma unroll
        for (int mt = 0; mt < 4; mt++)
#pragma unroll
            for (int r = 0; r < 4; r++) {
                float e = __expf(sacc[mt][r] * SCALEF);
                racc[mt] += e;
                ctmp[r]  += e;
            }
#pragma unroll
        for (int r = 0; r < 4; r++) {
            float v = ctmp[r];
            v += __shfl_xor(v, 1); v += __shfl_xor(v, 2);
            v += __shfl_xor(v, 4); v += __shfl_xor(v, 8);
            if (tx == 0) zacc[jt * 64 + w * 16 + q * 4 + r] = v;
        }
    }
#pragma unroll
    for (int mt = 0; mt < 4; mt++) {
        float v = racc[mt];
        v += __shfl_xor(v, 16);
        v += __shfl_xor(v, 32);
        if (q == 0) atomicAdd(&zrow[i0 + mt * 16 + tx], v);
    }
    __syncthreads();
#pragma unroll
    for (int k = 0; k < 4; k++)
        atomicAdd(&zcol[jbase + k * 256 + t], zacc[k * 256 + t]);
}

// ---------------------------------------------------------------------------
// K3: attn v7 — v6 dataflow (verified) at 4 blocks/CU.
// R5 diagnosis: all pipes <25% (Mfma 12%, VALU 14%, LDS ~20%, HBM 3%) with
// grid 512 = 2 blocks/CU (18% occupancy): pure latency/lockstep bound —
// the ~1-1.5k-cycle per-jt chain (frag reads -> QK -> exp -> barrier ->
// ds_write || PV -> barrier) has only 2 independent blocks to fill it.
// v7: j-range split 4-way (js 0..3, window 1024, jt 32->16), grid 1024 ->
// 4 blocks/CU (LDS 4x34.8=139KB, VGPR 116<=128 via launch_bounds(256,4)).
// 16 combos, 2 per XCD (combo=blk&15, XCD=blk&7): L2 set ~2MB/XCD.
// Cost: 4 j-partials per fus element (atomic traffic ~33MB = R0's proven
// epilogue volume). Register dataflow and epilogue unchanged.
// ---------------------------------------------------------------------------
__global__ __launch_bounds__(256, 4) void attn_mfma(const bf16_t* __restrict__ pfT,
                                                    const bf16_t* __restrict__ riT,
                                                    const bf16_t* __restrict__ pfC,
                                                    const bf16_t* __restrict__ riC,
                                                    const float* __restrict__ zrsum,
                                                    const float* __restrict__ zcsum,
                                                    float* __restrict__ fus)
{
    __shared__ char smem[34816];               // Bs[64][272B] + Vs[128][136B]
    bf16_t* As = (bf16_t*)smem;                // prologue A tile, aliases Bs
    char*   Bs = smem;                         // B tile, padded rows 272B
    char*   Vs = smem + 17408;                 // V tile, padded rows 136B
    float*  Rs = (float*)smem;                 // epilogue 64x65, aliases all

    const int t = threadIdx.x;
    const int blk = blockIdx.x;
    const int g = blk & 15;                    // combo; XCD = g&7 (2 combos/XCD)
    const int slot = blk >> 4;                 // 0..63 i-slot
    const int b = g & 1, mode = (g >> 1) & 1, js = g >> 2;   // js 0..3
    const bf16_t* At = (mode == 0 ? pfT : riT) + (size_t)b * NTOK * PCH;
    const bf16_t* Bt = (mode == 0 ? riT : pfT) + (size_t)b * NTOK * PCH;
    const bf16_t* Vc = (mode == 0 ? pfC : riC) + (size_t)b * PCH * NTOK;
    const float* wsum = (mode == 0 ? zcsum : zrsum) + (size_t)b * NTOK;
    const int lane = t & 63, w = t >> 6, tx = lane & 15, q = lane >> 4;
    const int h = w & 1, jh = w >> 1;
    const int i0 = slot * 64;
    const int jbase = js * 1024;               // 1024-token j-window, 16 jt
    const int sr = t >> 4, sc = t & 15;

    // ---- prologue: A tile -> LDS -> af regs
#pragma unroll
    for (int p = 0; p < 4; p++) {
        int i = p * 16 + sr;
        *(uint4*)&As[i * LDK + sc * 8] = *(const uint4*)&At[((size_t)(i0 + i)) * PCH + sc * 8];
    }
    __syncthreads();
    bf16x8 af[2][4];                           // this wave's 32 i-rows, held all kernel
#pragma unroll
    for (int mt = 0; mt < 2; mt++)
#pragma unroll
        for (int s = 0; s < 4; s++)
            af[mt][s] = *(bf16x8*)&As[(h * 32 + mt * 16 + tx) * LDK + s * 32 + q * 8];
    __syncthreads();                           // done with As before B overwrite

    const float* Wp = wsum + jbase + jh * 32 + q * 4;

    // staging bases: per-thread invariant; per-jt offsets are literals.
    const char* BsrcB = (const char*)Bt + (size_t)jbase * 256 + t * 16;
    const char* VsrcB = (const char*)Vc + (size_t)(t >> 3) * (NTOK * 2)
                        + (size_t)jbase * 2 + (t & 7) * 16;
    char* Bdst = Bs + (t >> 4) * 272 + (t & 15) * 16;
    char* Vdst = Vs + (t >> 3) * 136 + (t & 7) * 16;

    uint4 sB0, sB1, sB2, sB3, sV0, sV1, sV2, sV3;

#define STAGE_ISSUE(jtn)                                                        \
    sB0 = *(const uint4*)(BsrcB + (size_t)(jtn) * 16384);                       \
    sB1 = *(const uint4*)(BsrcB + (size_t)(jtn) * 16384 + 4096);                \
    sB2 = *(const uint4*)(BsrcB + (size_t)(jtn) * 16384 + 8192);                \
    sB3 = *(const uint4*)(BsrcB + (size_t)(jtn) * 16384 + 12288);               \
    sV0 = *(const uint4*)(VsrcB + (size_t)(jtn) * 128);                         \
    sV1 = *(const uint4*)(VsrcB + (size_t)(jtn) * 128 + (size_t)32 * NTOK * 2); \
    sV2 = *(const uint4*)(VsrcB + (size_t)(jtn) * 128 + (size_t)64 * NTOK * 2); \
    sV3 = *(const uint4*)(VsrcB + (size_t)(jtn) * 128 + (size_t)96 * NTOK * 2);

#define STAGE_WRITE()                  \
    *(uint4*)(Bdst)            = sB0;  \
    *(uint4*)(Bdst + 16 * 272) = sB1;  \
    *(uint4*)(Bdst + 32 * 272) = sB2;  \
    *(uint4*)(Bdst + 48 * 272) = sB3;  \
    *(uint4*)(Vdst)            = sV0;  \
    *(uint4*)(Vdst + 32 * 136) = sV1;  \
    *(uint4*)(Vdst + 64 * 136) = sV2;  \
    *(uint4*)(Vdst + 96 * 136) = sV3;

    // stage tile 0
    STAGE_ISSUE(0)
    STAGE_WRITE()
    float4 wv0 = *(const float4*)&Wp[0];
    float4 wv1 = *(const float4*)&Wp[16];
    float4 wn0 = wv0, wn1 = wv1;
    __syncthreads();

    floatx4 acc[2][8];                         // out[i=h*32+mt*16+q*4+r][d=c*16+tx]
#pragma unroll
    for (int mt = 0; mt < 2; mt++)
#pragma unroll
        for (int c = 0; c < 8; c++) acc[mt][c] = (floatx4){0.f, 0.f, 0.f, 0.f};

#pragma unroll 1
    for (int jt = 0; jt < 16; jt++) {
        // issue next tile's global loads early (consumed by ds_write below)
        if (jt < 15) {
            STAGE_ISSUE(jt + 1)
            wn0 = *(const float4*)&Wp[(jt + 1) * 64];
            wn1 = *(const float4*)&Wp[(jt + 1) * 64 + 16];
        }
        __builtin_amdgcn_sched_barrier(0);

        // fragment reads from LDS (current tile)
        bf16x8 bcur[2][4];
#pragma unroll
        for (int jm = 0; jm < 2; jm++)
#pragma unroll
            for (int s = 0; s < 4; s++)
                bcur[jm][s] = *(const bf16x8*)(Bs + (jh * 32 + jm * 16 + tx) * 272 + s * 64 + q * 16);
        bf16x8 vcur[8];
#pragma unroll
        for (int c = 0; c < 8; c++) {
            const char* vb = Vs + (tx + c * 16) * 136 + (jh * 32 + q * 4) * 2;
            bf16x4 vlo = *(const bf16x4*)vb;
            bf16x4 vhi = *(const bf16x4*)(vb + 32);
            vcur[c] = __builtin_shufflevector(vlo, vhi, 0, 1, 2, 3, 4, 5, 6, 7);
        }

        // QK: lane(q,tx) reg r = s[j = jbase+jt*64+jh*32+jm*16+q*4+r][i = i0+h*32+mt*16+tx]
        __builtin_amdgcn_s_setprio(1);
        floatx4 sx[2][2];
#pragma unroll
        for (int jm = 0; jm < 2; jm++)
#pragma unroll
            for (int mt = 0; mt < 2; mt++) {
                sx[jm][mt] = (floatx4){0.f, 0.f, 0.f, 0.f};
#pragma unroll
                for (int s = 0; s < 4; s++)
                    sx[jm][mt] = __builtin_amdgcn_mfma_f32_16x16x32_bf16(bcur[jm][s], af[mt][s], sx[jm][mt], 0, 0, 0);
            }
        __builtin_amdgcn_s_setprio(0);

        // exp + normalize, packed directly into PV A-frags (e<4: jm0, e>=4: jm1)
        float lz00 = __builtin_amdgcn_logf(wv0.x), lz01 = __builtin_amdgcn_logf(wv0.y);
        float lz02 = __builtin_amdgcn_logf(wv0.z), lz03 = __builtin_amdgcn_logf(wv0.w);
        float lz10 = __builtin_amdgcn_logf(wv1.x), lz11 = __builtin_amdgcn_logf(wv1.y);
        float lz12 = __builtin_amdgcn_logf(wv1.z), lz13 = __builtin_amdgcn_logf(wv1.w);
        bf16x8 ea0 = {
            (bf16_t)__builtin_amdgcn_exp2f(sx[0][0][0] * SCALE2 - lz00),
            (bf16_t)__builtin_amdgcn_exp2f(sx[0][0][1] * SCALE2 - lz01),
            (bf16_t)__builtin_amdgcn_exp2f(sx[0][0][2] * SCALE2 - lz02),
            (bf16_t)__builtin_amdgcn_exp2f(sx[0][0][3] * SCALE2 - lz03),
            (bf16_t)__builtin_amdgcn_exp2f(sx[1][0][0] * SCALE2 - lz10),
            (bf16_t)__builtin_amdgcn_exp2f(sx[1][0][1] * SCALE2 - lz11),
            (bf16_t)__builtin_amdgcn_exp2f(sx[1][0][2] * SCALE2 - lz12),
            (bf16_t)__builtin_amdgcn_exp2f(sx[1][0][3] * SCALE2 - lz13) };
        bf16x8 ea1 = {
            (bf16_t)__builtin_amdgcn_exp2f(sx[0][1][0] * SCALE2 - lz00),
            (bf16_t)__builtin_amdgcn_exp2f(sx[0][1][1] * SCALE2 - lz01),
            (bf16_t)__builtin_amdgcn_exp2f(sx[0][1][2] * SCALE2 - lz02),
            (bf16_t)__builtin_amdgcn_exp2f(sx[0][1][3] * SCALE2 - lz03),
            (bf16_t)__builtin_amdgcn_exp2f(sx[1][1][0] * SCALE2 - lz10),
            (bf16_t)__builtin_amdgcn_exp2f(sx[1][1][1] * SCALE2 - lz11),
            (bf16_t)__builtin_amdgcn_exp2f(sx[1][1][2] * SCALE2 - lz12),
            (bf16_t)__builtin_amdgcn_exp2f(sx[1][1][3] * SCALE2 - lz13) };

        __syncthreads();                       // all frag reads done block-wide

        // overwrite tiles with jt+1 (overlaps PV below)
        if (jt < 15) { STAGE_WRITE() }

        // PV: 16 independent mfma, acc[mt][c] += E[i][j] * V[j][d]
        __builtin_amdgcn_s_setprio(1);
#pragma unroll
        for (int c = 0; c < 8; c++) {
            acc[0][c] = __builtin_amdgcn_mfma_f32_16x16x32_bf16(ea0, vcur[c], acc[0][c], 0, 0, 0);
            acc[1][c] = __builtin_amdgcn_mfma_f32_16x16x32_bf16(ea1, vcur[c], acc[1][c], 0, 0, 0);
        }
        __builtin_amdgcn_s_setprio(0);

        __syncthreads();                       // writes visible for next iter
        wv0 = wn0; wv1 = wn1;
    }
#undef STAGE_ISSUE
#undef STAGE_WRITE

    // epilogue: cross-wave reduce (jh pairs) in LDS, then COALESCED atomics:
    // wave w owns rows w*16..w*16+15, lane = d (64 consecutive floats/instr).
    __syncthreads();
#pragma unroll
    for (int half = 0; half < 2; half++) {
        for (int k = t; k < 64 * 65; k += 256) Rs[k] = 0.f;
        __syncthreads();
#pragma unroll
        for (int mt = 0; mt < 2; mt++)
#pragma unroll
            for (int c = 0; c < 4; c++)
#pragma unroll
                for (int r = 0; r < 4; r++)
                    atomicAdd(&Rs[(h * 32 + mt * 16 + q * 4 + r) * 65 + c * 16 + tx],
                              acc[mt][half * 4 + c][r]);
        __syncthreads();
        {
            float* fo = fus + ((size_t)(b * NTOK + i0)) * 256 + mode * 128 + half * 64;
#pragma unroll
            for (int k = 0; k < 16; k++) {
                const int row = w * 16 + k;
                atomicAdd(&fo[(size_t)row * 256 + lane], Rs[row * 65 + lane]);
            }
        }
        __syncthreads();
    }
}

// ---------------------------------------------------------------------------
// K4: conv (MFMA) — out[o][n] = relu(bn(sum_c cw[o][c]*fus[n][c] + cb))
// ---------------------------------------------------------------------------
__global__ __launch_bounds__(256) void conv_mfma(const float* __restrict__ fus,
                                                 const float* __restrict__ cw,
                                                 const float* __restrict__ cb,
                                                 const float* __restrict__ g,
                                                 const float* __restrict__ be,
                                                 const float* __restrict__ mu,
                                                 const float* __restrict__ var,
                                                 float* __restrict__ out)
{
    const int t = threadIdx.x;
    const int n0 = blockIdx.x * 64, obase = blockIdx.y * 64, b = blockIdx.z;
    const int lane = t & 63, wv = t >> 6, tx = lane & 15, q = lane >> 4;
    const int n = n0 + wv * 16 + tx;
    const float* frow = fus + ((size_t)(b * NTOK + n)) * 256;

    floatx4 acc[4];
#pragma unroll
    for (int ot = 0; ot < 4; ot++) acc[ot] = (floatx4){0.f, 0.f, 0.f, 0.f};

#pragma unroll
    for (int s = 0; s < 8; s++) {
        float4 f0 = *(const float4*)&frow[s * 32 + q * 8];
        float4 f1 = *(const float4*)&frow[s * 32 + q * 8 + 4];
        bf16x8 bf;
        bf[0] = (bf16_t)f0.x; bf[1] = (bf16_t)f0.y; bf[2] = (bf16_t)f0.z; bf[3] = (bf16_t)f0.w;
        bf[4] = (bf16_t)f1.x; bf[5] = (bf16_t)f1.y; bf[6] = (bf16_t)f1.z; bf[7] = (bf16_t)f1.w;
#pragma unroll
        for (int ot = 0; ot < 4; ot++) {
            const float* wr = cw + (size_t)(obase + ot * 16 + tx) * 256 + s * 32 + q * 8;
            float4 x0 = *(const float4*)wr;
            float4 x1 = *(const float4*)(wr + 4);
            bf16x8 af;
            af[0] = (bf16_t)x0.x; af[1] = (bf16_t)x0.y; af[2] = (bf16_t)x0.z; af[3] = (bf16_t)x0.w;
            af[4] = (bf16_t)x1.x; af[5] = (bf16_t)x1.y; af[6] = (bf16_t)x1.z; af[7] = (bf16_t)x1.w;
            acc[ot] = __builtin_amdgcn_mfma_f32_16x16x32_bf16(af, bf, acc[ot], 0, 0, 0);
        }
    }

#pragma unroll
    for (int ot = 0; ot < 4; ot++)
#pragma unroll
        for (int r = 0; r < 4; r++) {
            const int o = obase + ot * 16 + q * 4 + r;
            const float sc = g[o] * rsqrtf(var[o] + 1e-5f);
            const float b0 = be[o] + (cb[o] - mu[o]) * sc;
            float y = acc[ot][r] * sc + b0;
            out[((size_t)(b * OCH + o)) * NTOK + n] = fmaxf(y, 0.f);
        }
}

// ---------------------------------------------------------------------------
extern "C" void kernel_launch(void* const* d_in, const int* in_sizes, int n_in,
                              void* d_out, int out_size, void* d_ws, size_t ws_size,
                              hipStream_t stream)
{
    const float* pf   = (const float*)d_in[0];
    const float* img  = (const float*)d_in[1];
    const float* fc2w = (const float*)d_in[2];
    const float* fc2b = (const float*)d_in[3];
    const float* cw   = (const float*)d_in[4];
    const float* cb   = (const float*)d_in[5];
    const float* g    = (const float*)d_in[6];
    const float* be   = (const float*)d_in[7];
    const float* mu   = (const float*)d_in[8];
    const float* var  = (const float*)d_in[9];
    float* out = (float*)d_out;

    // ws layout: proven footprint (16,842,752 B). imgT aliases fus region
    // (dead after fc2; fus is zeroed inside stats which runs after fc2).
    float* fus   = (float*)d_ws;                              // 8 MB
    float* zrsum = fus + (size_t)NB * NTOK * 256;             // 32 KB
    float* zcsum = zrsum + NB * NTOK;                         // 32 KB (contiguous after zrsum)
    bf16_t* pfC = (bf16_t*)(zcsum + NB * NTOK);               // 2 MB
    bf16_t* pfT = pfC + (size_t)NB * PCH * NTOK;              // 2 MB
    bf16_t* riC = pfT + (size_t)NB * NTOK * PCH;              // 2 MB
    bf16_t* riT = riC + (size_t)NB * PCH * NTOK;              // 2 MB
    bf16_t* imgT = (bf16_t*)fus;                              // 4 MB alias

    pack_all  <<<dim3(64, 6, NB), 256, 0, stream>>>(pf, img, pfC, pfT, imgT);
    fc2_mfma  <<<dim3(64, 2, NB), 256, 0, stream>>>(imgT, fc2w, fc2b, riC, riT, zrsum);
    stats_mfma<<<dim3(512),       256, 0, stream>>>(pfT, riT, zrsum, zcsum, fus);
    attn_mfma <<<dim3(1024),      256, 0, stream>>>(pfT, riT, pfC, riC, zrsum, zcsum, fus);
    conv_mfma <<<dim3(64, 2, NB), 256, 0, stream>>>(fus, cw, cb, g, be, mu, var, out);
}

// Round 7
// 328.382 us; speedup vs baseline: 2.1564x; 2.1564x over previous
//
#include <hip/hip_runtime.h>
#include <math.h>

// Problem constants
#define NTOK 4096
#define PCH  128
#define ICH  256
#define OCH  128
#define NB   2
#define SCALEF 0.08838834764831845f   // 1/sqrt(128)
#define SCALE2 0.12751743f            // SCALEF * log2(e)

typedef __bf16 bf16_t;
typedef __attribute__((ext_vector_type(8))) __bf16 bf16x8;
typedef __attribute__((ext_vector_type(4))) __bf16 bf16x4;
typedef __attribute__((ext_vector_type(4))) float floatx4;

#define LDK 136   // padded row length (bf16) for k=128 tiles

// ---------------------------------------------------------------------------
// K0: merged pack — y<2: pf -> pfC + pfT;  y>=2: img -> imgT (token-major)
// ---------------------------------------------------------------------------
__global__ __launch_bounds__(256) void pack_all(const float* __restrict__ pf,
                                                const float* __restrict__ img,
                                                bf16_t* __restrict__ pfC,
                                                bf16_t* __restrict__ pfT,
                                                bf16_t* __restrict__ imgT)
{
    __shared__ float Ls[64][65];
    const int t = threadIdx.x;
    const int n0 = blockIdx.x * 64, b = blockIdx.z;
    const bool ispf = blockIdx.y < 2;
    const int d0 = ispf ? blockIdx.y * 64 : (blockIdx.y - 2) * 64;
    const float* src = (ispf ? pf + ((size_t)(b * PCH + d0)) * NTOK
                             : img + ((size_t)(b * ICH + d0)) * NTOK) + n0;
#pragma unroll
    for (int p = 0; p < 4; p++) {
        int d = p * 16 + (t >> 4), c = t & 15;
        float4 v = *(const float4*)&src[d * NTOK + c * 4];
        Ls[d][c * 4 + 0] = v.x; Ls[d][c * 4 + 1] = v.y;
        Ls[d][c * 4 + 2] = v.z; Ls[d][c * 4 + 3] = v.w;
        if (ispf) {
            bf16x4 o = { (bf16_t)v.x, (bf16_t)v.y, (bf16_t)v.z, (bf16_t)v.w };
            *(bf16x4*)&pfC[((size_t)(b * PCH + d0 + d)) * NTOK + n0 + c * 4] = o;
        }
    }
    __syncthreads();
#pragma unroll
    for (int p = 0; p < 2; p++) {
        int n = p * 32 + (t >> 3), c = t & 7;
        bf16x8 o;
#pragma unroll
        for (int k = 0; k < 8; k++) o[k] = (bf16_t)Ls[c * 8 + k][n];
        if (ispf)
            *(bf16x8*)&pfT[((size_t)(b * NTOK + n0 + n)) * PCH + d0 + c * 8] = o;
        else
            *(bf16x8*)&imgT[((size_t)(b * NTOK + n0 + n)) * ICH + d0 + c * 8] = o;
    }
}

// ---------------------------------------------------------------------------
// K1: fc2 (MFMA) — ri[p][n] = sum_c w[p][c]*img[c][n] + bias[p]
// Also zeroes the zsum buffers (16384 floats) in its prologue.
// ---------------------------------------------------------------------------
__global__ __launch_bounds__(256) void fc2_mfma(const bf16_t* __restrict__ imgT,
                                                const float* __restrict__ w,
                                                const float* __restrict__ bias,
                                                bf16_t* __restrict__ riC,
                                                bf16_t* __restrict__ riT,
                                                float* __restrict__ zsums)
{
    const int t = threadIdx.x;
    if (blockIdx.y == 0 && blockIdx.z == 0)
        zsums[blockIdx.x * 256 + t] = 0.f;       // 64 blocks x 256 = 16384 floats

    const int n0 = blockIdx.x * 64, pbase = blockIdx.y * 64, b = blockIdx.z;
    const int lane = t & 63, wv = t >> 6, tx = lane & 15, q = lane >> 4;
    const int n = n0 + wv * 16 + tx;
    const bf16_t* trow = imgT + ((size_t)(b * NTOK + n)) * ICH;

    floatx4 acc[4];
#pragma unroll
    for (int ot = 0; ot < 4; ot++) acc[ot] = (floatx4){0.f, 0.f, 0.f, 0.f};

#pragma unroll
    for (int s = 0; s < 8; s++) {
        bf16x8 bf = *(const bf16x8*)&trow[s * 32 + q * 8];
#pragma unroll
        for (int ot = 0; ot < 4; ot++) {
            const float* wr = w + (size_t)(pbase + ot * 16 + tx) * ICH + s * 32 + q * 8;
            float4 x0 = *(const float4*)wr;
            float4 x1 = *(const float4*)(wr + 4);
            bf16x8 af;
            af[0] = (bf16_t)x0.x; af[1] = (bf16_t)x0.y; af[2] = (bf16_t)x0.z; af[3] = (bf16_t)x0.w;
            af[4] = (bf16_t)x1.x; af[5] = (bf16_t)x1.y; af[6] = (bf16_t)x1.z; af[7] = (bf16_t)x1.w;
            acc[ot] = __builtin_amdgcn_mfma_f32_16x16x32_bf16(af, bf, acc[ot], 0, 0, 0);
        }
    }

#pragma unroll
    for (int ot = 0; ot < 4; ot++) {
        bf16x4 tv;
#pragma unroll
        for (int r = 0; r < 4; r++) {
            const int p = pbase + ot * 16 + q * 4 + r;
            float v = acc[ot][r] + bias[p];
            tv[r] = (bf16_t)v;
            riC[((size_t)(b * PCH + p)) * NTOK + n] = (bf16_t)v;
        }
        *(bf16x4*)&riT[((size_t)(b * NTOK + n)) * PCH + pbase + ot * 16 + q * 4] = tv;
    }
}

// ---------------------------------------------------------------------------
// K2: stats v5 + XCD swizzle + fus-zero prologue (unchanged).
// ---------------------------------------------------------------------------
__global__ __launch_bounds__(256, 4) void stats_mfma(const bf16_t* __restrict__ pfT,
                                                     const bf16_t* __restrict__ riT,
                                                     float* __restrict__ zr,
                                                     float* __restrict__ zc,
                                                     float* __restrict__ fus)
{
    __shared__ bf16_t As[64 * LDK];
    __shared__ float zacc[1024];
    const int t = threadIdx.x;
    const int blk = blockIdx.x;

    { // zero fus: 512 blocks x 256 thr x 4 float4 = 2,097,152 floats exactly
        float4* f4 = (float4*)fus + ((size_t)blk * 256 + t) * 4;
        f4[0] = float4{0.f, 0.f, 0.f, 0.f};
        f4[1] = float4{0.f, 0.f, 0.f, 0.f};
        f4[2] = float4{0.f, 0.f, 0.f, 0.f};
        f4[3] = float4{0.f, 0.f, 0.f, 0.f};
    }

    const int g = blk & 7, slot = blk >> 3;      // XCD-aware decode
    const int b = g & 1, js = g >> 1;
    const bf16_t* At = pfT + (size_t)b * NTOK * PCH;
    const bf16_t* Bt = riT + (size_t)b * NTOK * PCH;
    float* zrow = zr + (size_t)b * NTOK;
    float* zcol = zc + (size_t)b * NTOK;
    const int lane = t & 63, w = t >> 6, tx = lane & 15, q = lane >> 4;
    const int i0 = slot * 64;
    const int jbase = js * 1024;
    const int sr = t >> 4, sc = t & 15;
    const bf16_t* Brow = Bt + (size_t)(jbase + w * 16 + tx) * PCH;

    bf16x8 bcur[4];
#pragma unroll
    for (int s = 0; s < 4; s++)
        bcur[s] = *(const bf16x8*)&Brow[s * 32 + q * 8];
#pragma unroll
    for (int p = 0; p < 4; p++) {
        int i = p * 16 + sr;
        *(uint4*)&As[i * LDK + sc * 8] = *(const uint4*)&At[((size_t)(i0 + i)) * PCH + sc * 8];
    }
    __syncthreads();
    bf16x8 af[4][4];
#pragma unroll
    for (int mt = 0; mt < 4; mt++)
#pragma unroll
        for (int s = 0; s < 4; s++)
            af[mt][s] = *(bf16x8*)&As[(mt * 16 + tx) * LDK + s * 32 + q * 8];

    float racc[4] = {0.f, 0.f, 0.f, 0.f};
    for (int jt = 0; jt < 16; jt++) {
        __builtin_amdgcn_s_barrier();            // pacing only
        floatx4 sacc[4];
#pragma unroll
        for (int mt = 0; mt < 4; mt++) {
            sacc[mt] = (floatx4){0.f, 0.f, 0.f, 0.f};
#pragma unroll
            for (int s = 0; s < 4; s++)
                sacc[mt] = __builtin_amdgcn_mfma_f32_16x16x32_bf16(bcur[s], af[mt][s], sacc[mt], 0, 0, 0);
        }
        if (jt < 15) {
            const bf16_t* bn = Brow + (size_t)(jt + 1) * 64 * PCH;
#pragma unroll
            for (int s = 0; s < 4; s++)
                bcur[s] = *(const bf16x8*)&bn[s * 32 + q * 8];
        }

        float ctmp[4] = {0.f, 0.f, 0.f, 0.f};
#pragma unroll
        for (int mt = 0; mt < 4; mt++)
#pragma unroll
            for (int r = 0; r < 4; r++) {
                float e = __expf(sacc[mt][r] * SCALEF);
                racc[mt] += e;
                ctmp[r]  += e;
            }
#pragma unroll
        for (int r = 0; r < 4; r++) {
            float v = ctmp[r];
            v += __shfl_xor(v, 1); v += __shfl_xor(v, 2);
            v += __shfl_xor(v, 4); v += __shfl_xor(v, 8);
            if (tx == 0) zacc[jt * 64 + w * 16 + q * 4 + r] = v;
        }
    }
#pragma unroll
    for (int mt = 0; mt < 4; mt++) {
        float v = racc[mt];
        v += __shfl_xor(v, 16);
        v += __shfl_xor(v, 32);
        if (q == 0) atomicAdd(&zrow[i0 + mt * 16 + tx], v);
    }
    __syncthreads();
#pragma unroll
    for (int k = 0; k < 4; k++)
        atomicAdd(&zcol[jbase + k * 256 + t], zacc[k * 256 + t]);
}

// ---------------------------------------------------------------------------
// K3: attn v8 — per-wave private LDS tiles, ZERO barriers in the main loop.
// R6 lesson: 4 blocks/CU impossible (VGPR cap 128 < ~190 live -> mass spill).
// R5 analysis: at 2 blocks/CU the cost is the 2-barrier/jt lockstep (each
// barrier drains vmcnt/lgkmcnt for all 4 waves; ~8k cyc/jt vs ~1.5k of work).
// v8: each wave owns a private 16KB LDS region (B 8KB + V 8KB, XOR-swizzled
// instead of padded so 4x16KB = 64KB static). Same-wave DS ops execute in
// order, so "read frags of jt, then overwrite with jt+1" is race-free with
// no synchronization at all. Waves drift freely; 8 waves/CU pipeline each
// other. Cost: B/V staged per-wave (2x duplication across h-pair) — all L2
// hits. Swizzles (write/read consistent involutions):
//   B[32][256B]: unit16 ^= row&7      (frag reads 2-way = free)
//   V[128][64B]: unit16 ^= (d>>2)&3   (frag reads 2-way = free)
// Staging in 16 individually named uint4 regs (no arrays/lambdas — the
// R1/R4 alloca lessons). Verified register dataflow + epilogue unchanged.
// ---------------------------------------------------------------------------
__global__ __launch_bounds__(256, 2) void attn_mfma(const bf16_t* __restrict__ pfT,
                                                    const bf16_t* __restrict__ riT,
                                                    const bf16_t* __restrict__ pfC,
                                                    const bf16_t* __restrict__ riC,
                                                    const float* __restrict__ zrsum,
                                                    const float* __restrict__ zcsum,
                                                    float* __restrict__ fus)
{
    __shared__ char smem[65536];               // 4 waves x (B 8KB + V 8KB)
    bf16_t* As = (bf16_t*)smem;                // prologue A tile (17408B), aliased
    float*  Rs = (float*)smem;                 // epilogue 64x65 f32, aliased

    const int t = threadIdx.x;
    const int blk = blockIdx.x;
    const int g = blk & 7;                     // combo -> XCD
    const int slot = blk >> 3;                 // 0..63 i-slot
    const int b = g & 1, mode = (g >> 1) & 1, js = g >> 2;
    const bf16_t* At = (mode == 0 ? pfT : riT) + (size_t)b * NTOK * PCH;
    const bf16_t* Bt = (mode == 0 ? riT : pfT) + (size_t)b * NTOK * PCH;
    const bf16_t* Vc = (mode == 0 ? pfC : riC) + (size_t)b * PCH * NTOK;
    const float* wsum = (mode == 0 ? zcsum : zrsum) + (size_t)b * NTOK;
    const int lane = t & 63, w = t >> 6, tx = lane & 15, q = lane >> 4;
    const int h = w & 1, jh = w >> 1;
    const int i0 = slot * 64;
    const int jbase = js * 2048;
    const int sr = t >> 4, sc = t & 15;

    // ---- prologue: A tile -> LDS -> af regs (block-wide, 2 barriers)
#pragma unroll
    for (int p = 0; p < 4; p++) {
        int i = p * 16 + sr;
        *(uint4*)&As[i * LDK + sc * 8] = *(const uint4*)&At[((size_t)(i0 + i)) * PCH + sc * 8];
    }
    __syncthreads();
    bf16x8 af[2][4];                           // this wave's 32 i-rows, held all kernel
#pragma unroll
    for (int mt = 0; mt < 2; mt++)
#pragma unroll
        for (int s = 0; s < 4; s++)
            af[mt][s] = *(bf16x8*)&As[(h * 32 + mt * 16 + tx) * LDK + s * 32 + q * 8];
    __syncthreads();                           // all af reads done before tile-0 staging

    // per-wave LDS regions
    char* Bw = smem + w * 16384;               // B tile [32 rows][256B], swizzled
    char* Vw = Bw + 8192;                      // V tile [128 rows][64B], swizzled

    // global staging bases (per-lane invariant; per-jt offsets are literals)
    const char* BsrcB = (const char*)Bt + (size_t)(jbase + jh * 32) * 256 + lane * 16;
    const char* VsrcB = (const char*)Vc + (size_t)(lane >> 2) * (NTOK * 2)
                        + (size_t)(jbase + jh * 32) * 2 + (lane & 3) * 16;
    // LDS write bases (swizzled):
    //  B: row = p*4 + (lane>>4), unit16 = (lane&15) ^ (row&7)
    //     = bu ^ ((p&1)<<2) with bu = (lane&15)^(lane>>4)  -> even/odd-p bases
    //  V: row = p*16 + (lane>>2), unit16 = (lane&3) ^ ((lane>>4)&3) (p-free)
    const int bu = (lane & 15) ^ (lane >> 4);
    char* BdstE = Bw + (lane >> 4) * 256 + (bu << 4);
    char* BdstO = Bw + (lane >> 4) * 256 + ((bu ^ 4) << 4);
    char* Vdst  = Vw + (lane >> 2) * 64 + (((lane & 3) ^ ((lane >> 4) & 3)) << 4);

    const float* Wp = wsum + jbase + jh * 32 + q * 4;
    // V frag read base: row=tx (+c*16 later), unit16 = (q>>1) ^ ((tx>>2)&3),
    // sub-offset (q&1)*8; hi half = lo byte-address ^ 32 (unit16 ^ 2).
    const int vroff = tx * 64 + (((q >> 1) ^ ((tx >> 2) & 3)) << 4) + ((q & 1) << 3);

    uint4 sB0, sB1, sB2, sB3, sB4, sB5, sB6, sB7;
    uint4 sV0, sV1, sV2, sV3, sV4, sV5, sV6, sV7;

#define STAGE_ISSUE(jtn)                                                       \
    sB0 = *(const uint4*)(BsrcB + (size_t)(jtn) * 16384);                      \
    sB1 = *(const uint4*)(BsrcB + (size_t)(jtn) * 16384 + 1024);               \
    sB2 = *(const uint4*)(BsrcB + (size_t)(jtn) * 16384 + 2048);               \
    sB3 = *(const uint4*)(BsrcB + (size_t)(jtn) * 16384 + 3072);               \
    sB4 = *(const uint4*)(BsrcB + (size_t)(jtn) * 16384 + 4096);               \
    sB5 = *(const uint4*)(BsrcB + (size_t)(jtn) * 16384 + 5120);               \
    sB6 = *(const uint4*)(BsrcB + (size_t)(jtn) * 16384 + 6144);               \
    sB7 = *(const uint4*)(BsrcB + (size_t)(jtn) * 16384 + 7168);               \
    sV0 = *(const uint4*)(VsrcB + (size_t)(jtn) * 128);                        \
    sV1 = *(const uint4*)(VsrcB + (size_t)(jtn) * 128 + (size_t)1 * 131072);   \
    sV2 = *(const uint4*)(VsrcB + (size_t)(jtn) * 128 + (size_t)2 * 131072);   \
    sV3 = *(const uint4*)(VsrcB + (size_t)(jtn) * 128 + (size_t)3 * 131072);   \
    sV4 = *(const uint4*)(VsrcB + (size_t)(jtn) * 128 + (size_t)4 * 131072);   \
    sV5 = *(const uint4*)(VsrcB + (size_t)(jtn) * 128 + (size_t)5 * 131072);   \
    sV6 = *(const uint4*)(VsrcB + (size_t)(jtn) * 128 + (size_t)6 * 131072);   \
    sV7 = *(const uint4*)(VsrcB + (size_t)(jtn) * 128 + (size_t)7 * 131072);

#define STAGE_WRITE()                 \
    *(uint4*)(BdstE)         = sB0;   \
    *(uint4*)(BdstO + 1024)  = sB1;   \
    *(uint4*)(BdstE + 2048)  = sB2;   \
    *(uint4*)(BdstO + 3072)  = sB3;   \
    *(uint4*)(BdstE + 4096)  = sB4;   \
    *(uint4*)(BdstO + 5120)  = sB5;   \
    *(uint4*)(BdstE + 6144)  = sB6;   \
    *(uint4*)(BdstO + 7168)  = sB7;   \
    *(uint4*)(Vdst)          = sV0;   \
    *(uint4*)(Vdst + 1024)   = sV1;   \
    *(uint4*)(Vdst + 2048)   = sV2;   \
    *(uint4*)(Vdst + 3072)   = sV3;   \
    *(uint4*)(Vdst + 4096)   = sV4;   \
    *(uint4*)(Vdst + 5120)   = sV5;   \
    *(uint4*)(Vdst + 6144)   = sV6;   \
    *(uint4*)(Vdst + 7168)   = sV7;

    // stage tile 0 (wave-private; no barrier needed after)
    STAGE_ISSUE(0)
    STAGE_WRITE()
    float4 wv0 = *(const float4*)&Wp[0];
    float4 wv1 = *(const float4*)&Wp[16];
    float4 wn0 = wv0, wn1 = wv1;

    floatx4 acc[2][8];                         // out[i=h*32+mt*16+q*4+r][d=c*16+tx]
#pragma unroll
    for (int mt = 0; mt < 2; mt++)
#pragma unroll
        for (int c = 0; c < 8; c++) acc[mt][c] = (floatx4){0.f, 0.f, 0.f, 0.f};

#pragma unroll 1
    for (int jt = 0; jt < 32; jt++) {
        // issue next tile's global loads early (land during QK+exp)
        if (jt < 31) {
            STAGE_ISSUE(jt + 1)
            wn0 = *(const float4*)&Wp[(jt + 1) * 64];
            wn1 = *(const float4*)&Wp[(jt + 1) * 64 + 16];
        }
        __builtin_amdgcn_sched_barrier(0);

        // fragment reads from own LDS (jt's data; same-wave DS order => safe)
        bf16x8 bcur[2][4];
#pragma unroll
        for (int jm = 0; jm < 2; jm++)
#pragma unroll
            for (int s = 0; s < 4; s++)
                bcur[jm][s] = *(const bf16x8*)(Bw + ((jm * 16 + tx) << 8)
                                               + ((((s * 4) + q) ^ (tx & 7)) << 4));
        bf16x8 vcur[8];
#pragma unroll
        for (int c = 0; c < 8; c++) {
            const char* vp = Vw + vroff + c * 1024;
            bf16x4 vlo = *(const bf16x4*)vp;
            bf16x4 vhi = *(const bf16x4*)((const char*)((size_t)vp ^ 32));
            vcur[c] = __builtin_shufflevector(vlo, vhi, 0, 1, 2, 3, 4, 5, 6, 7);
        }

        // QK: lane(q,tx) reg r = s[j = jbase+jt*64+jh*32+jm*16+q*4+r][i = i0+h*32+mt*16+tx]
        __builtin_amdgcn_s_setprio(1);
        floatx4 sx[2][2];
#pragma unroll
        for (int jm = 0; jm < 2; jm++)
#pragma unroll
            for (int mt = 0; mt < 2; mt++) {
                sx[jm][mt] = (floatx4){0.f, 0.f, 0.f, 0.f};
#pragma unroll
                for (int s = 0; s < 4; s++)
                    sx[jm][mt] = __builtin_amdgcn_mfma_f32_16x16x32_bf16(bcur[jm][s], af[mt][s], sx[jm][mt], 0, 0, 0);
            }
        __builtin_amdgcn_s_setprio(0);

        // exp + normalize, packed directly into PV A-frags (e<4: jm0, e>=4: jm1)
        float lz00 = __builtin_amdgcn_logf(wv0.x), lz01 = __builtin_amdgcn_logf(wv0.y);
        float lz02 = __builtin_amdgcn_logf(wv0.z), lz03 = __builtin_amdgcn_logf(wv0.w);
        float lz10 = __builtin_amdgcn_logf(wv1.x), lz11 = __builtin_amdgcn_logf(wv1.y);
        float lz12 = __builtin_amdgcn_logf(wv1.z), lz13 = __builtin_amdgcn_logf(wv1.w);
        bf16x8 ea0 = {
            (bf16_t)__builtin_amdgcn_exp2f(sx[0][0][0] * SCALE2 - lz00),
            (bf16_t)__builtin_amdgcn_exp2f(sx[0][0][1] * SCALE2 - lz01),
            (bf16_t)__builtin_amdgcn_exp2f(sx[0][0][2] * SCALE2 - lz02),
            (bf16_t)__builtin_amdgcn_exp2f(sx[0][0][3] * SCALE2 - lz03),
            (bf16_t)__builtin_amdgcn_exp2f(sx[1][0][0] * SCALE2 - lz10),
            (bf16_t)__builtin_amdgcn_exp2f(sx[1][0][1] * SCALE2 - lz11),
            (bf16_t)__builtin_amdgcn_exp2f(sx[1][0][2] * SCALE2 - lz12),
            (bf16_t)__builtin_amdgcn_exp2f(sx[1][0][3] * SCALE2 - lz13) };
        bf16x8 ea1 = {
            (bf16_t)__builtin_amdgcn_exp2f(sx[0][1][0] * SCALE2 - lz00),
            (bf16_t)__builtin_amdgcn_exp2f(sx[0][1][1] * SCALE2 - lz01),
            (bf16_t)__builtin_amdgcn_exp2f(sx[0][1][2] * SCALE2 - lz02),
            (bf16_t)__builtin_amdgcn_exp2f(sx[0][1][3] * SCALE2 - lz03),
            (bf16_t)__builtin_amdgcn_exp2f(sx[1][1][0] * SCALE2 - lz10),
            (bf16_t)__builtin_amdgcn_exp2f(sx[1][1][1] * SCALE2 - lz11),
            (bf16_t)__builtin_amdgcn_exp2f(sx[1][1][2] * SCALE2 - lz12),
            (bf16_t)__builtin_amdgcn_exp2f(sx[1][1][3] * SCALE2 - lz13) };

        // overwrite own tiles with jt+1 (after frag reads in program order;
        // same-wave DS in-order execution makes this race-free, no barrier)
        if (jt < 31) { STAGE_WRITE() }

        // PV: 16 independent mfma, acc[mt][c] += E[i][j] * V[j][d]
        __builtin_amdgcn_s_setprio(1);
#pragma unroll
        for (int c = 0; c < 8; c++) {
            acc[0][c] = __builtin_amdgcn_mfma_f32_16x16x32_bf16(ea0, vcur[c], acc[0][c], 0, 0, 0);
            acc[1][c] = __builtin_amdgcn_mfma_f32_16x16x32_bf16(ea1, vcur[c], acc[1][c], 0, 0, 0);
        }
        __builtin_amdgcn_s_setprio(0);

        wv0 = wn0; wv1 = wn1;
    }
#undef STAGE_ISSUE
#undef STAGE_WRITE

    // epilogue: cross-wave reduce (jh pairs) in LDS, then COALESCED atomics:
    // wave w owns rows w*16..w*16+15, lane = d (64 consecutive floats/instr).
    __syncthreads();
#pragma unroll
    for (int half = 0; half < 2; half++) {
        for (int k = t; k < 64 * 65; k += 256) Rs[k] = 0.f;
        __syncthreads();
#pragma unroll
        for (int mt = 0; mt < 2; mt++)
#pragma unroll
            for (int c = 0; c < 4; c++)
#pragma unroll
                for (int r = 0; r < 4; r++)
                    atomicAdd(&Rs[(h * 32 + mt * 16 + q * 4 + r) * 65 + c * 16 + tx],
                              acc[mt][half * 4 + c][r]);
        __syncthreads();
        {
            float* fo = fus + ((size_t)(b * NTOK + i0)) * 256 + mode * 128 + half * 64;
#pragma unroll
            for (int k = 0; k < 16; k++) {
                const int row = w * 16 + k;
                atomicAdd(&fo[(size_t)row * 256 + lane], Rs[row * 65 + lane]);
            }
        }
        __syncthreads();
    }
}

// ---------------------------------------------------------------------------
// K4: conv (MFMA) — out[o][n] = relu(bn(sum_c cw[o][c]*fus[n][c] + cb))
// ---------------------------------------------------------------------------
__global__ __launch_bounds__(256) void conv_mfma(const float* __restrict__ fus,
                                                 const float* __restrict__ cw,
                                                 const float* __restrict__ cb,
                                                 const float* __restrict__ g,
                                                 const float* __restrict__ be,
                                                 const float* __restrict__ mu,
                                                 const float* __restrict__ var,
                                                 float* __restrict__ out)
{
    const int t = threadIdx.x;
    const int n0 = blockIdx.x * 64, obase = blockIdx.y * 64, b = blockIdx.z;
    const int lane = t & 63, wv = t >> 6, tx = lane & 15, q = lane >> 4;
    const int n = n0 + wv * 16 + tx;
    const float* frow = fus + ((size_t)(b * NTOK + n)) * 256;

    floatx4 acc[4];
#pragma unroll
    for (int ot = 0; ot < 4; ot++) acc[ot] = (floatx4){0.f, 0.f, 0.f, 0.f};

#pragma unroll
    for (int s = 0; s < 8; s++) {
        float4 f0 = *(const float4*)&frow[s * 32 + q * 8];
        float4 f1 = *(const float4*)&frow[s * 32 + q * 8 + 4];
        bf16x8 bf;
        bf[0] = (bf16_t)f0.x; bf[1] = (bf16_t)f0.y; bf[2] = (bf16_t)f0.z; bf[3] = (bf16_t)f0.w;
        bf[4] = (bf16_t)f1.x; bf[5] = (bf16_t)f1.y; bf[6] = (bf16_t)f1.z; bf[7] = (bf16_t)f1.w;
#pragma unroll
        for (int ot = 0; ot < 4; ot++) {
            const float* wr = cw + (size_t)(obase + ot * 16 + tx) * 256 + s * 32 + q * 8;
            float4 x0 = *(const float4*)wr;
            float4 x1 = *(const float4*)(wr + 4);
            bf16x8 af;
            af[0] = (bf16_t)x0.x; af[1] = (bf16_t)x0.y; af[2] = (bf16_t)x0.z; af[3] = (bf16_t)x0.w;
            af[4] = (bf16_t)x1.x; af[5] = (bf16_t)x1.y; af[6] = (bf16_t)x1.z; af[7] = (bf16_t)x1.w;
            acc[ot] = __builtin_amdgcn_mfma_f32_16x16x32_bf16(af, bf, acc[ot], 0, 0, 0);
        }
    }

#pragma unroll
    for (int ot = 0; ot < 4; ot++)
#pragma unroll
        for (int r = 0; r < 4; r++) {
            const int o = obase + ot * 16 + q * 4 + r;
            const float sc = g[o] * rsqrtf(var[o] + 1e-5f);
            const float b0 = be[o] + (cb[o] - mu[o]) * sc;
            float y = acc[ot][r] * sc + b0;
            out[((size_t)(b * OCH + o)) * NTOK + n] = fmaxf(y, 0.f);
        }
}

// ---------------------------------------------------------------------------
extern "C" void kernel_launch(void* const* d_in, const int* in_sizes, int n_in,
                              void* d_out, int out_size, void* d_ws, size_t ws_size,
                              hipStream_t stream)
{
    const float* pf   = (const float*)d_in[0];
    const float* img  = (const float*)d_in[1];
    const float* fc2w = (const float*)d_in[2];
    const float* fc2b = (const float*)d_in[3];
    const float* cw   = (const float*)d_in[4];
    const float* cb   = (const float*)d_in[5];
    const float* g    = (const float*)d_in[6];
    const float* be   = (const float*)d_in[7];
    const float* mu   = (const float*)d_in[8];
    const float* var  = (const float*)d_in[9];
    float* out = (float*)d_out;

    // ws layout: proven footprint (16,842,752 B). imgT aliases fus region
    // (dead after fc2; fus is zeroed inside stats which runs after fc2).
    float* fus   = (float*)d_ws;                              // 8 MB
    float* zrsum = fus + (size_t)NB * NTOK * 256;             // 32 KB
    float* zcsum = zrsum + NB * NTOK;                         // 32 KB (contiguous after zrsum)
    bf16_t* pfC = (bf16_t*)(zcsum + NB * NTOK);               // 2 MB
    bf16_t* pfT = pfC + (size_t)NB * PCH * NTOK;              // 2 MB
    bf16_t* riC = pfT + (size_t)NB * NTOK * PCH;              // 2 MB
    bf16_t* riT = riC + (size_t)NB * PCH * NTOK;              // 2 MB
    bf16_t* imgT = (bf16_t*)fus;                              // 4 MB alias

    pack_all  <<<dim3(64, 6, NB), 256, 0, stream>>>(pf, img, pfC, pfT, imgT);
    fc2_mfma  <<<dim3(64, 2, NB), 256, 0, stream>>>(imgT, fc2w, fc2b, riC, riT, zrsum);
    stats_mfma<<<dim3(512),       256, 0, stream>>>(pfT, riT, zrsum, zcsum, fus);
    attn_mfma <<<dim3(512),       256, 0, stream>>>(pfT, riT, pfC, riC, zrsum, zcsum, fus);
    conv_mfma <<<dim3(64, 2, NB), 256, 0, stream>>>(fus, cw, cb, g, be, mu, var, out);
}

// Round 8
// 282.315 us; speedup vs baseline: 2.5082x; 1.1632x over previous
//
#include <hip/hip_runtime.h>
#include <math.h>

// Problem constants
#define NTOK 4096
#define PCH  128
#define ICH  256
#define OCH  128
#define NB   2
#define SCALEF 0.08838834764831845f   // 1/sqrt(128)
#define SCALE2 0.12751743f            // SCALEF * log2(e)

typedef __bf16 bf16_t;
typedef __attribute__((ext_vector_type(8))) __bf16 bf16x8;
typedef __attribute__((ext_vector_type(4))) __bf16 bf16x4;
typedef __attribute__((ext_vector_type(4))) float floatx4;

#define LDK 136   // padded row length (bf16) for k=128 tiles

// ---------------------------------------------------------------------------
// K0: merged pack — y<2: pf -> pfC + pfT;  y>=2: img -> imgT (token-major)
// ---------------------------------------------------------------------------
__global__ __launch_bounds__(256) void pack_all(const float* __restrict__ pf,
                                                const float* __restrict__ img,
                                                bf16_t* __restrict__ pfC,
                                                bf16_t* __restrict__ pfT,
                                                bf16_t* __restrict__ imgT)
{
    __shared__ float Ls[64][65];
    const int t = threadIdx.x;
    const int n0 = blockIdx.x * 64, b = blockIdx.z;
    const bool ispf = blockIdx.y < 2;
    const int d0 = ispf ? blockIdx.y * 64 : (blockIdx.y - 2) * 64;
    const float* src = (ispf ? pf + ((size_t)(b * PCH + d0)) * NTOK
                             : img + ((size_t)(b * ICH + d0)) * NTOK) + n0;
#pragma unroll
    for (int p = 0; p < 4; p++) {
        int d = p * 16 + (t >> 4), c = t & 15;
        float4 v = *(const float4*)&src[d * NTOK + c * 4];
        Ls[d][c * 4 + 0] = v.x; Ls[d][c * 4 + 1] = v.y;
        Ls[d][c * 4 + 2] = v.z; Ls[d][c * 4 + 3] = v.w;
        if (ispf) {
            bf16x4 o = { (bf16_t)v.x, (bf16_t)v.y, (bf16_t)v.z, (bf16_t)v.w };
            *(bf16x4*)&pfC[((size_t)(b * PCH + d0 + d)) * NTOK + n0 + c * 4] = o;
        }
    }
    __syncthreads();
#pragma unroll
    for (int p = 0; p < 2; p++) {
        int n = p * 32 + (t >> 3), c = t & 7;
        bf16x8 o;
#pragma unroll
        for (int k = 0; k < 8; k++) o[k] = (bf16_t)Ls[c * 8 + k][n];
        if (ispf)
            *(bf16x8*)&pfT[((size_t)(b * NTOK + n0 + n)) * PCH + d0 + c * 8] = o;
        else
            *(bf16x8*)&imgT[((size_t)(b * NTOK + n0 + n)) * ICH + d0 + c * 8] = o;
    }
}

// ---------------------------------------------------------------------------
// K1: fc2 (MFMA) — ri[p][n] = sum_c w[p][c]*img[c][n] + bias[p]
// Also zeroes the zsum buffers (16384 floats) in its prologue.
// ---------------------------------------------------------------------------
__global__ __launch_bounds__(256) void fc2_mfma(const bf16_t* __restrict__ imgT,
                                                const float* __restrict__ w,
                                                const float* __restrict__ bias,
                                                bf16_t* __restrict__ riC,
                                                bf16_t* __restrict__ riT,
                                                float* __restrict__ zsums)
{
    const int t = threadIdx.x;
    if (blockIdx.y == 0 && blockIdx.z == 0)
        zsums[blockIdx.x * 256 + t] = 0.f;       // 64 blocks x 256 = 16384 floats

    const int n0 = blockIdx.x * 64, pbase = blockIdx.y * 64, b = blockIdx.z;
    const int lane = t & 63, wv = t >> 6, tx = lane & 15, q = lane >> 4;
    const int n = n0 + wv * 16 + tx;
    const bf16_t* trow = imgT + ((size_t)(b * NTOK + n)) * ICH;

    floatx4 acc[4];
#pragma unroll
    for (int ot = 0; ot < 4; ot++) acc[ot] = (floatx4){0.f, 0.f, 0.f, 0.f};

#pragma unroll
    for (int s = 0; s < 8; s++) {
        bf16x8 bf = *(const bf16x8*)&trow[s * 32 + q * 8];
#pragma unroll
        for (int ot = 0; ot < 4; ot++) {
            const float* wr = w + (size_t)(pbase + ot * 16 + tx) * ICH + s * 32 + q * 8;
            float4 x0 = *(const float4*)wr;
            float4 x1 = *(const float4*)(wr + 4);
            bf16x8 af;
            af[0] = (bf16_t)x0.x; af[1] = (bf16_t)x0.y; af[2] = (bf16_t)x0.z; af[3] = (bf16_t)x0.w;
            af[4] = (bf16_t)x1.x; af[5] = (bf16_t)x1.y; af[6] = (bf16_t)x1.z; af[7] = (bf16_t)x1.w;
            acc[ot] = __builtin_amdgcn_mfma_f32_16x16x32_bf16(af, bf, acc[ot], 0, 0, 0);
        }
    }

#pragma unroll
    for (int ot = 0; ot < 4; ot++) {
        bf16x4 tv;
#pragma unroll
        for (int r = 0; r < 4; r++) {
            const int p = pbase + ot * 16 + q * 4 + r;
            float v = acc[ot][r] + bias[p];
            tv[r] = (bf16_t)v;
            riC[((size_t)(b * PCH + p)) * NTOK + n] = (bf16_t)v;
        }
        *(bf16x4*)&riT[((size_t)(b * NTOK + n)) * PCH + pbase + ot * 16 + q * 4] = tv;
    }
}

// ---------------------------------------------------------------------------
// K2: stats v5 + XCD swizzle + fus-zero prologue (unchanged).
// ---------------------------------------------------------------------------
__global__ __launch_bounds__(256, 4) void stats_mfma(const bf16_t* __restrict__ pfT,
                                                     const bf16_t* __restrict__ riT,
                                                     float* __restrict__ zr,
                                                     float* __restrict__ zc,
                                                     float* __restrict__ fus)
{
    __shared__ bf16_t As[64 * LDK];
    __shared__ float zacc[1024];
    const int t = threadIdx.x;
    const int blk = blockIdx.x;

    { // zero fus: 512 blocks x 256 thr x 4 float4 = 2,097,152 floats exactly
        float4* f4 = (float4*)fus + ((size_t)blk * 256 + t) * 4;
        f4[0] = float4{0.f, 0.f, 0.f, 0.f};
        f4[1] = float4{0.f, 0.f, 0.f, 0.f};
        f4[2] = float4{0.f, 0.f, 0.f, 0.f};
        f4[3] = float4{0.f, 0.f, 0.f, 0.f};
    }

    const int g = blk & 7, slot = blk >> 3;      // XCD-aware decode
    const int b = g & 1, js = g >> 1;
    const bf16_t* At = pfT + (size_t)b * NTOK * PCH;
    const bf16_t* Bt = riT + (size_t)b * NTOK * PCH;
    float* zrow = zr + (size_t)b * NTOK;
    float* zcol = zc + (size_t)b * NTOK;
    const int lane = t & 63, w = t >> 6, tx = lane & 15, q = lane >> 4;
    const int i0 = slot * 64;
    const int jbase = js * 1024;
    const int sr = t >> 4, sc = t & 15;
    const bf16_t* Brow = Bt + (size_t)(jbase + w * 16 + tx) * PCH;

    bf16x8 bcur[4];
#pragma unroll
    for (int s = 0; s < 4; s++)
        bcur[s] = *(const bf16x8*)&Brow[s * 32 + q * 8];
#pragma unroll
    for (int p = 0; p < 4; p++) {
        int i = p * 16 + sr;
        *(uint4*)&As[i * LDK + sc * 8] = *(const uint4*)&At[((size_t)(i0 + i)) * PCH + sc * 8];
    }
    __syncthreads();
    bf16x8 af[4][4];
#pragma unroll
    for (int mt = 0; mt < 4; mt++)
#pragma unroll
        for (int s = 0; s < 4; s++)
            af[mt][s] = *(bf16x8*)&As[(mt * 16 + tx) * LDK + s * 32 + q * 8];

    float racc[4] = {0.f, 0.f, 0.f, 0.f};
    for (int jt = 0; jt < 16; jt++) {
        __builtin_amdgcn_s_barrier();            // pacing only
        floatx4 sacc[4];
#pragma unroll
        for (int mt = 0; mt < 4; mt++) {
            sacc[mt] = (floatx4){0.f, 0.f, 0.f, 0.f};
#pragma unroll
            for (int s = 0; s < 4; s++)
                sacc[mt] = __builtin_amdgcn_mfma_f32_16x16x32_bf16(bcur[s], af[mt][s], sacc[mt], 0, 0, 0);
        }
        if (jt < 15) {
            const bf16_t* bn = Brow + (size_t)(jt + 1) * 64 * PCH;
#pragma unroll
            for (int s = 0; s < 4; s++)
                bcur[s] = *(const bf16x8*)&bn[s * 32 + q * 8];
        }

        float ctmp[4] = {0.f, 0.f, 0.f, 0.f};
#pragma unroll
        for (int mt = 0; mt < 4; mt++)
#pragma unroll
            for (int r = 0; r < 4; r++) {
                float e = __expf(sacc[mt][r] * SCALEF);
                racc[mt] += e;
                ctmp[r]  += e;
            }
#pragma unroll
        for (int r = 0; r < 4; r++) {
            float v = ctmp[r];
            v += __shfl_xor(v, 1); v += __shfl_xor(v, 2);
            v += __shfl_xor(v, 4); v += __shfl_xor(v, 8);
            if (tx == 0) zacc[jt * 64 + w * 16 + q * 4 + r] = v;
        }
    }
#pragma unroll
    for (int mt = 0; mt < 4; mt++) {
        float v = racc[mt];
        v += __shfl_xor(v, 16);
        v += __shfl_xor(v, 32);
        if (q == 0) atomicAdd(&zrow[i0 + mt * 16 + tx], v);
    }
    __syncthreads();
#pragma unroll
    for (int k = 0; k < 4; k++)
        atomicAdd(&zcol[jbase + k * 256 + t], zacc[k * 256 + t]);
}

// ---------------------------------------------------------------------------
// K3: attn v9 — v6 body byte-identical, grid scaled for occupancy.
// R7 lesson: forcing occupancy via launch_bounds caps VGPR -> spills.
// v6's ACTUAL resources (VGPR 116 <= 128, LDS 34.8KB) already permit
// 4 blocks/CU — the only reason R5 ran at 2/CU was grid=512 (2 per CU
// available, period). v9: j-split 4-way (js 0..3, window 1024, jt 16),
// grid 1024, launch_bounds STAYS (256,2) so the allocator is unconstrained
// (~116 regs) and hardware schedules 4 blocks/CU naturally.
// 16 combos, 2 per XCD sharing the same A matrix (XCD k hosts combos k,
// k+8 which differ only in js bit1): L2 set = A 1MB + 2x(B .5 + V .5)
// = 3MB < 4MB. Epilogue partials double (proven-cheap coalesced atomics,
// ~33MB = R0's volume). Everything inside the jt loop is unchanged v6.
// ---------------------------------------------------------------------------
__global__ __launch_bounds__(256, 2) void attn_mfma(const bf16_t* __restrict__ pfT,
                                                    const bf16_t* __restrict__ riT,
                                                    const bf16_t* __restrict__ pfC,
                                                    const bf16_t* __restrict__ riC,
                                                    const float* __restrict__ zrsum,
                                                    const float* __restrict__ zcsum,
                                                    float* __restrict__ fus)
{
    __shared__ char smem[34816];               // Bs[64][272B] + Vs[128][136B]
    bf16_t* As = (bf16_t*)smem;                // prologue A tile, aliases Bs
    char*   Bs = smem;                         // B tile, padded rows 272B
    char*   Vs = smem + 17408;                 // V tile, padded rows 136B
    float*  Rs = (float*)smem;                 // epilogue 64x65, aliases all

    const int t = threadIdx.x;
    const int blk = blockIdx.x;
    const int g = blk & 15;                    // combo; XCD = blk&7 (combos k,k+8 share A)
    const int slot = blk >> 4;                 // 0..63 i-slot
    const int b = g & 1, mode = (g >> 1) & 1, js = g >> 2;   // js 0..3
    const bf16_t* At = (mode == 0 ? pfT : riT) + (size_t)b * NTOK * PCH;
    const bf16_t* Bt = (mode == 0 ? riT : pfT) + (size_t)b * NTOK * PCH;
    const bf16_t* Vc = (mode == 0 ? pfC : riC) + (size_t)b * PCH * NTOK;
    const float* wsum = (mode == 0 ? zcsum : zrsum) + (size_t)b * NTOK;
    const int lane = t & 63, w = t >> 6, tx = lane & 15, q = lane >> 4;
    const int h = w & 1, jh = w >> 1;
    const int i0 = slot * 64;
    const int jbase = js * 1024;               // 1024-token j-window, 16 jt
    const int sr = t >> 4, sc = t & 15;

    // ---- prologue: A tile -> LDS -> af regs
#pragma unroll
    for (int p = 0; p < 4; p++) {
        int i = p * 16 + sr;
        *(uint4*)&As[i * LDK + sc * 8] = *(const uint4*)&At[((size_t)(i0 + i)) * PCH + sc * 8];
    }
    __syncthreads();
    bf16x8 af[2][4];                           // this wave's 32 i-rows, held all kernel
#pragma unroll
    for (int mt = 0; mt < 2; mt++)
#pragma unroll
        for (int s = 0; s < 4; s++)
            af[mt][s] = *(bf16x8*)&As[(h * 32 + mt * 16 + tx) * LDK + s * 32 + q * 8];
    __syncthreads();                           // done with As before B overwrite

    const float* Wp = wsum + jbase + jh * 32 + q * 4;

    // staging bases: per-thread invariant; per-jt offsets are literals.
    const char* BsrcB = (const char*)Bt + (size_t)jbase * 256 + t * 16;
    const char* VsrcB = (const char*)Vc + (size_t)(t >> 3) * (NTOK * 2)
                        + (size_t)jbase * 2 + (t & 7) * 16;
    char* Bdst = Bs + (t >> 4) * 272 + (t & 15) * 16;
    char* Vdst = Vs + (t >> 3) * 136 + (t & 7) * 16;

    uint4 sB0, sB1, sB2, sB3, sV0, sV1, sV2, sV3;

#define STAGE_ISSUE(jtn)                                                        \
    sB0 = *(const uint4*)(BsrcB + (size_t)(jtn) * 16384);                       \
    sB1 = *(const uint4*)(BsrcB + (size_t)(jtn) * 16384 + 4096);                \
    sB2 = *(const uint4*)(BsrcB + (size_t)(jtn) * 16384 + 8192);                \
    sB3 = *(const uint4*)(BsrcB + (size_t)(jtn) * 16384 + 12288);               \
    sV0 = *(const uint4*)(VsrcB + (size_t)(jtn) * 128);                         \
    sV1 = *(const uint4*)(VsrcB + (size_t)(jtn) * 128 + (size_t)32 * NTOK * 2); \
    sV2 = *(const uint4*)(VsrcB + (size_t)(jtn) * 128 + (size_t)64 * NTOK * 2); \
    sV3 = *(const uint4*)(VsrcB + (size_t)(jtn) * 128 + (size_t)96 * NTOK * 2);

#define STAGE_WRITE()                  \
    *(uint4*)(Bdst)            = sB0;  \
    *(uint4*)(Bdst + 16 * 272) = sB1;  \
    *(uint4*)(Bdst + 32 * 272) = sB2;  \
    *(uint4*)(Bdst + 48 * 272) = sB3;  \
    *(uint4*)(Vdst)            = sV0;  \
    *(uint4*)(Vdst + 32 * 136) = sV1;  \
    *(uint4*)(Vdst + 64 * 136) = sV2;  \
    *(uint4*)(Vdst + 96 * 136) = sV3;

    // stage tile 0
    STAGE_ISSUE(0)
    STAGE_WRITE()
    float4 wv0 = *(const float4*)&Wp[0];
    float4 wv1 = *(const float4*)&Wp[16];
    float4 wn0 = wv0, wn1 = wv1;
    __syncthreads();

    floatx4 acc[2][8];                         // out[i=h*32+mt*16+q*4+r][d=c*16+tx]
#pragma unroll
    for (int mt = 0; mt < 2; mt++)
#pragma unroll
        for (int c = 0; c < 8; c++) acc[mt][c] = (floatx4){0.f, 0.f, 0.f, 0.f};

#pragma unroll 1
    for (int jt = 0; jt < 16; jt++) {
        // issue next tile's global loads early (consumed by ds_write below)
        if (jt < 15) {
            STAGE_ISSUE(jt + 1)
            wn0 = *(const float4*)&Wp[(jt + 1) * 64];
            wn1 = *(const float4*)&Wp[(jt + 1) * 64 + 16];
        }
        __builtin_amdgcn_sched_barrier(0);

        // fragment reads from LDS (current tile)
        bf16x8 bcur[2][4];
#pragma unroll
        for (int jm = 0; jm < 2; jm++)
#pragma unroll
            for (int s = 0; s < 4; s++)
                bcur[jm][s] = *(const bf16x8*)(Bs + (jh * 32 + jm * 16 + tx) * 272 + s * 64 + q * 16);
        bf16x8 vcur[8];
#pragma unroll
        for (int c = 0; c < 8; c++) {
            const char* vb = Vs + (tx + c * 16) * 136 + (jh * 32 + q * 4) * 2;
            bf16x4 vlo = *(const bf16x4*)vb;
            bf16x4 vhi = *(const bf16x4*)(vb + 32);
            vcur[c] = __builtin_shufflevector(vlo, vhi, 0, 1, 2, 3, 4, 5, 6, 7);
        }

        // QK: lane(q,tx) reg r = s[j = jbase+jt*64+jh*32+jm*16+q*4+r][i = i0+h*32+mt*16+tx]
        __builtin_amdgcn_s_setprio(1);
        floatx4 sx[2][2];
#pragma unroll
        for (int jm = 0; jm < 2; jm++)
#pragma unroll
            for (int mt = 0; mt < 2; mt++) {
                sx[jm][mt] = (floatx4){0.f, 0.f, 0.f, 0.f};
#pragma unroll
                for (int s = 0; s < 4; s++)
                    sx[jm][mt] = __builtin_amdgcn_mfma_f32_16x16x32_bf16(bcur[jm][s], af[mt][s], sx[jm][mt], 0, 0, 0);
            }
        __builtin_amdgcn_s_setprio(0);

        // exp + normalize, packed directly into PV A-frags (e<4: jm0, e>=4: jm1)
        float lz00 = __builtin_amdgcn_logf(wv0.x), lz01 = __builtin_amdgcn_logf(wv0.y);
        float lz02 = __builtin_amdgcn_logf(wv0.z), lz03 = __builtin_amdgcn_logf(wv0.w);
        float lz10 = __builtin_amdgcn_logf(wv1.x), lz11 = __builtin_amdgcn_logf(wv1.y);
        float lz12 = __builtin_amdgcn_logf(wv1.z), lz13 = __builtin_amdgcn_logf(wv1.w);
        bf16x8 ea0 = {
            (bf16_t)__builtin_amdgcn_exp2f(sx[0][0][0] * SCALE2 - lz00),
            (bf16_t)__builtin_amdgcn_exp2f(sx[0][0][1] * SCALE2 - lz01),
            (bf16_t)__builtin_amdgcn_exp2f(sx[0][0][2] * SCALE2 - lz02),
            (bf16_t)__builtin_amdgcn_exp2f(sx[0][0][3] * SCALE2 - lz03),
            (bf16_t)__builtin_amdgcn_exp2f(sx[1][0][0] * SCALE2 - lz10),
            (bf16_t)__builtin_amdgcn_exp2f(sx[1][0][1] * SCALE2 - lz11),
            (bf16_t)__builtin_amdgcn_exp2f(sx[1][0][2] * SCALE2 - lz12),
            (bf16_t)__builtin_amdgcn_exp2f(sx[1][0][3] * SCALE2 - lz13) };
        bf16x8 ea1 = {
            (bf16_t)__builtin_amdgcn_exp2f(sx[0][1][0] * SCALE2 - lz00),
            (bf16_t)__builtin_amdgcn_exp2f(sx[0][1][1] * SCALE2 - lz01),
            (bf16_t)__builtin_amdgcn_exp2f(sx[0][1][2] * SCALE2 - lz02),
            (bf16_t)__builtin_amdgcn_exp2f(sx[0][1][3] * SCALE2 - lz03),
            (bf16_t)__builtin_amdgcn_exp2f(sx[1][1][0] * SCALE2 - lz10),
            (bf16_t)__builtin_amdgcn_exp2f(sx[1][1][1] * SCALE2 - lz11),
            (bf16_t)__builtin_amdgcn_exp2f(sx[1][1][2] * SCALE2 - lz12),
            (bf16_t)__builtin_amdgcn_exp2f(sx[1][1][3] * SCALE2 - lz13) };

        __syncthreads();                       // all frag reads done block-wide

        // overwrite tiles with jt+1 (overlaps PV below)
        if (jt < 15) { STAGE_WRITE() }

        // PV: 16 independent mfma, acc[mt][c] += E[i][j] * V[j][d]
        __builtin_amdgcn_s_setprio(1);
#pragma unroll
        for (int c = 0; c < 8; c++) {
            acc[0][c] = __builtin_amdgcn_mfma_f32_16x16x32_bf16(ea0, vcur[c], acc[0][c], 0, 0, 0);
            acc[1][c] = __builtin_amdgcn_mfma_f32_16x16x32_bf16(ea1, vcur[c], acc[1][c], 0, 0, 0);
        }
        __builtin_amdgcn_s_setprio(0);

        __syncthreads();                       // writes visible for next iter
        wv0 = wn0; wv1 = wn1;
    }
#undef STAGE_ISSUE
#undef STAGE_WRITE

    // epilogue: cross-wave reduce (jh pairs) in LDS, then COALESCED atomics:
    // wave w owns rows w*16..w*16+15, lane = d (64 consecutive floats/instr).
    __syncthreads();
#pragma unroll
    for (int half = 0; half < 2; half++) {
        for (int k = t; k < 64 * 65; k += 256) Rs[k] = 0.f;
        __syncthreads();
#pragma unroll
        for (int mt = 0; mt < 2; mt++)
#pragma unroll
            for (int c = 0; c < 4; c++)
#pragma unroll
                for (int r = 0; r < 4; r++)
                    atomicAdd(&Rs[(h * 32 + mt * 16 + q * 4 + r) * 65 + c * 16 + tx],
                              acc[mt][half * 4 + c][r]);
        __syncthreads();
        {
            float* fo = fus + ((size_t)(b * NTOK + i0)) * 256 + mode * 128 + half * 64;
#pragma unroll
            for (int k = 0; k < 16; k++) {
                const int row = w * 16 + k;
                atomicAdd(&fo[(size_t)row * 256 + lane], Rs[row * 65 + lane]);
            }
        }
        __syncthreads();
    }
}

// ---------------------------------------------------------------------------
// K4: conv (MFMA) — out[o][n] = relu(bn(sum_c cw[o][c]*fus[n][c] + cb))
// ---------------------------------------------------------------------------
__global__ __launch_bounds__(256) void conv_mfma(const float* __restrict__ fus,
                                                 const float* __restrict__ cw,
                                                 const float* __restrict__ cb,
                                                 const float* __restrict__ g,
                                                 const float* __restrict__ be,
                                                 const float* __restrict__ mu,
                                                 const float* __restrict__ var,
                                                 float* __restrict__ out)
{
    const int t = threadIdx.x;
    const int n0 = blockIdx.x * 64, obase = blockIdx.y * 64, b = blockIdx.z;
    const int lane = t & 63, wv = t >> 6, tx = lane & 15, q = lane >> 4;
    const int n = n0 + wv * 16 + tx;
    const float* frow = fus + ((size_t)(b * NTOK + n)) * 256;

    floatx4 acc[4];
#pragma unroll
    for (int ot = 0; ot < 4; ot++) acc[ot] = (floatx4){0.f, 0.f, 0.f, 0.f};

#pragma unroll
    for (int s = 0; s < 8; s++) {
        float4 f0 = *(const float4*)&frow[s * 32 + q * 8];
        float4 f1 = *(const float4*)&frow[s * 32 + q * 8 + 4];
        bf16x8 bf;
        bf[0] = (bf16_t)f0.x; bf[1] = (bf16_t)f0.y; bf[2] = (bf16_t)f0.z; bf[3] = (bf16_t)f0.w;
        bf[4] = (bf16_t)f1.x; bf[5] = (bf16_t)f1.y; bf[6] = (bf16_t)f1.z; bf[7] = (bf16_t)f1.w;
#pragma unroll
        for (int ot = 0; ot < 4; ot++) {
            const float* wr = cw + (size_t)(obase + ot * 16 + tx) * 256 + s * 32 + q * 8;
            float4 x0 = *(const float4*)wr;
            float4 x1 = *(const float4*)(wr + 4);
            bf16x8 af;
            af[0] = (bf16_t)x0.x; af[1] = (bf16_t)x0.y; af[2] = (bf16_t)x0.z; af[3] = (bf16_t)x0.w;
            af[4] = (bf16_t)x1.x; af[5] = (bf16_t)x1.y; af[6] = (bf16_t)x1.z; af[7] = (bf16_t)x1.w;
            acc[ot] = __builtin_amdgcn_mfma_f32_16x16x32_bf16(af, bf, acc[ot], 0, 0, 0);
        }
    }

#pragma unroll
    for (int ot = 0; ot < 4; ot++)
#pragma unroll
        for (int r = 0; r < 4; r++) {
            const int o = obase + ot * 16 + q * 4 + r;
            const float sc = g[o] * rsqrtf(var[o] + 1e-5f);
            const float b0 = be[o] + (cb[o] - mu[o]) * sc;
            float y = acc[ot][r] * sc + b0;
            out[((size_t)(b * OCH + o)) * NTOK + n] = fmaxf(y, 0.f);
        }
}

// ---------------------------------------------------------------------------
extern "C" void kernel_launch(void* const* d_in, const int* in_sizes, int n_in,
                              void* d_out, int out_size, void* d_ws, size_t ws_size,
                              hipStream_t stream)
{
    const float* pf   = (const float*)d_in[0];
    const float* img  = (const float*)d_in[1];
    const float* fc2w = (const float*)d_in[2];
    const float* fc2b = (const float*)d_in[3];
    const float* cw   = (const float*)d_in[4];
    const float* cb   = (const float*)d_in[5];
    const float* g    = (const float*)d_in[6];
    const float* be   = (const float*)d_in[7];
    const float* mu   = (const float*)d_in[8];
    const float* var  = (const float*)d_in[9];
    float* out = (float*)d_out;

    // ws layout: proven footprint (16,842,752 B). imgT aliases fus region
    // (dead after fc2; fus is zeroed inside stats which runs after fc2).
    float* fus   = (float*)d_ws;                              // 8 MB
    float* zrsum = fus + (size_t)NB * NTOK * 256;             // 32 KB
    float* zcsum = zrsum + NB * NTOK;                         // 32 KB (contiguous after zrsum)
    bf16_t* pfC = (bf16_t*)(zcsum + NB * NTOK);               // 2 MB
    bf16_t* pfT = pfC + (size_t)NB * PCH * NTOK;              // 2 MB
    bf16_t* riC = pfT + (size_t)NB * NTOK * PCH;              // 2 MB
    bf16_t* riT = riC + (size_t)NB * PCH * NTOK;              // 2 MB
    bf16_t* imgT = (bf16_t*)fus;                              // 4 MB alias

    pack_all  <<<dim3(64, 6, NB), 256, 0, stream>>>(pf, img, pfC, pfT, imgT);
    fc2_mfma  <<<dim3(64, 2, NB), 256, 0, stream>>>(imgT, fc2w, fc2b, riC, riT, zrsum);
    stats_mfma<<<dim3(512),       256, 0, stream>>>(pfT, riT, zrsum, zcsum, fus);
    attn_mfma <<<dim3(1024),      256, 0, stream>>>(pfT, riT, pfC, riC, zrsum, zcsum, fus);
    conv_mfma <<<dim3(64, 2, NB), 256, 0, stream>>>(fus, cw, cb, g, be, mu, var, out);
}